// Round 6
// baseline (610.367 us; speedup 1.0000x reference)
//
#include <hip/hip_runtime.h>
#include <hip/hip_cooperative_groups.h>
#include <stdint.h>

namespace cg = cooperative_groups;

// RelationalMSG fully fused (R6): one cooperative kernel, 6 grid syncs.
//   P0 convert W1/W2 to MFMA B-frag bf16 + zero hist
//   P1 hist(dst) + gemm1: [Ys|Yd] = x@[W1a|W1b] (+b1 on Yd), permuted col layout
//   P2 per-1024-chunk exclusive scan of counts
//   P3 apply chunk offsets -> rowptr, cursor
//   P4 counting-sort scatter: ssrc grouped by dst
//   P5 CSR aggregation: aggb[n] = sum relu(Ys[src]+Yd[n])   (no fp32 atomics)
//   P6 gemm2: out = x + relu([x;agg]@W2+b2)
// N=50000, E=600000, D=128. Fallback: R5's 9-dispatch path if coop launch fails.

typedef __attribute__((ext_vector_type(8))) short short8;   // 8 bf16 (MFMA A/B frag)
typedef __attribute__((ext_vector_type(4))) float floatx4;  // MFMA C/D frag

#define D 128

static __device__ __forceinline__ unsigned short f2bf(float f) {
    union { float f; unsigned int u; } v; v.f = f;
    unsigned int r = (v.u + 0x7fffu + ((v.u >> 16) & 1u)) >> 16; // RNE
    return (unsigned short)r;
}
static __device__ __forceinline__ float bflo(unsigned int u) {
    union { unsigned int u; float f; } v; v.u = u << 16; return v.f;
}
static __device__ __forceinline__ float bfhi(unsigned int u) {
    union { unsigned int u; float f; } v; v.u = u & 0xffff0000u; return v.f;
}
static __device__ __forceinline__ short8 cvt8(const float* p) {
    float4 f0 = *(const float4*)p;
    float4 f1 = *(const float4*)(p + 4);
    short8 t;
    t[0] = (short)f2bf(f0.x); t[1] = (short)f2bf(f0.y);
    t[2] = (short)f2bf(f0.z); t[3] = (short)f2bf(f0.w);
    t[4] = (short)f2bf(f1.x); t[5] = (short)f2bf(f1.y);
    t[6] = (short)f2bf(f1.z); t[7] = (short)f2bf(f1.w);
    return t;
}

// ---------------- fused cooperative kernel ----------------
__global__ __launch_bounds__(256, 4) void k_fused(
    const float* __restrict__ x, const int* __restrict__ esrc, const int* __restrict__ edst,
    const float* __restrict__ W1, const float* __restrict__ b1,
    const float* __restrict__ W2, const float* __restrict__ b2,
    float* __restrict__ out,
    unsigned short* __restrict__ Ys, unsigned short* __restrict__ Yd,
    unsigned short* __restrict__ aggb,
    unsigned short* __restrict__ w1f, unsigned short* __restrict__ w2f,
    int* __restrict__ rowptr, int* __restrict__ cursor, int* __restrict__ cnt,
    int* __restrict__ bsum, int* __restrict__ ssrc,
    int N, int E, int nTiles)
{
    cg::grid_group gg = cg::this_grid();
    const int tid  = threadIdx.x;
    const int bid  = blockIdx.x;
    const int nBlk = gridDim.x;
    const int gtid = bid * 256 + tid;
    const int gsz  = nBlk * 256;
    const int lane = tid & 63, w = tid >> 6;
    const int quad = lane >> 4, col = lane & 15;
    __shared__ int sh[256];
    __shared__ int boff[64];

    // ---- P0: weight conversion + zero hist ----
    for (int gid = gtid; gid < 65536; gid += gsz) {
        if (gid < 32768) {
            int t = gid;
            int j = t & 7, ln = (t >> 3) & 63, ct = (t >> 9) & 15, kk = t >> 13;
            int k = kk * 32 + (ln >> 4) * 8 + j;
            int c = ct * 16 + (ln & 15);
            float v = (c < 128) ? W1[k * 128 + c] : W1[(128 + k) * 128 + (c - 128)];
            w1f[t] = f2bf(v);
        } else {
            int t = gid - 32768;
            int j = t & 7, ln = (t >> 3) & 63, ct = (t >> 9) & 7, kk = t >> 12;
            int k = kk * 32 + (ln >> 4) * 8 + j;
            int c = ct * 16 + (ln & 15);
            int row = (k < 128) ? k : (128 + ((k - 128) & 7) * 16 + ((k - 128) >> 3));
            w2f[t] = f2bf(W2[row * 128 + c]);
        }
    }
    for (int i = gtid; i < N; i += gsz) cnt[i] = 0;
    gg.sync();

    // ---- P1: histogram + gemm1 ----
    for (int i = gtid; i < E; i += gsz) atomicAdd(&cnt[edst[i]], 1);
    {
        short8 wf[4][4];
#pragma unroll
        for (int kk = 0; kk < 4; kk++)
#pragma unroll
            for (int j = 0; j < 4; j++)
                wf[kk][j] = ((const short8*)w1f)[(kk * 16 + w * 4 + j) * 64 + lane];
        float bias[4];
#pragma unroll
        for (int j = 0; j < 4; j++)
            bias[j] = (w >= 2) ? b1[(((w & 1) * 4 + j)) * 16 + col] : 0.f;
        unsigned short* Yhalf = (w < 2) ? Ys : Yd;
        const int ctb = (w & 1) * 4;   // permuted store base: pos = col16*8 + ct

        for (int t = bid; t < nTiles; t += nBlk) {
            const int n0 = t * 16;
            int nr = n0 + col; if (nr >= N) nr = N - 1;
            floatx4 acc[4];
#pragma unroll
            for (int j = 0; j < 4; j++)
#pragma unroll
                for (int q = 0; q < 4; q++) acc[j][q] = 0.f;
#pragma unroll
            for (int kk = 0; kk < 4; kk++) {
                short8 a = cvt8(x + (long)nr * D + kk * 32 + quad * 8);
#pragma unroll
                for (int j = 0; j < 4; j++)
                    acc[j] = __builtin_amdgcn_mfma_f32_16x16x32_bf16(a, wf[kk][j], acc[j], 0, 0, 0);
            }
#pragma unroll
            for (int r = 0; r < 4; r++) {
                int n = n0 + quad * 4 + r;
                if (n < N) {
                    ushort4 o;
                    o.x = f2bf(acc[0][r] + bias[0]);
                    o.y = f2bf(acc[1][r] + bias[1]);
                    o.z = f2bf(acc[2][r] + bias[2]);
                    o.w = f2bf(acc[3][r] + bias[3]);
                    *(ushort4*)(Yhalf + (long)n * D + col * 8 + ctb) = o;
                }
            }
        }
    }
    gg.sync();

    // ---- P2: per-chunk scan (1024 bins per block, 4/thread) ----
    const int nChunk = (N + 1023) >> 10;   // 49
    if (bid < nChunk) {
        int base = bid * 1024 + tid * 4;
        int c[4];
#pragma unroll
        for (int j = 0; j < 4; j++)
            c[j] = (base + j < N) ? cnt[base + j] : 0;
        int s = c[0] + c[1] + c[2] + c[3];
        sh[tid] = s; __syncthreads();
        for (int off = 1; off < 256; off <<= 1) {
            int t = (tid >= off) ? sh[tid - off] : 0;
            __syncthreads();
            sh[tid] += t;
            __syncthreads();
        }
        int run = sh[tid] - s;   // exclusive prefix of this thread's 4 bins
#pragma unroll
        for (int j = 0; j < 4; j++) {
            if (base + j < N) { rowptr[base + j] = run; run += c[j]; }
        }
        if (tid == 255) bsum[bid] = sh[255];
    }
    gg.sync();

    // ---- P3: chunk-offset scan (redundant per block) + apply ----
    if (tid < 64) {
        int v = (tid < nChunk) ? bsum[tid] : 0;
        int incl = v;
        for (int off = 1; off < 64; off <<= 1) {
            int t = __shfl_up(incl, off, 64);
            if (tid >= off) incl += t;
        }
        boff[tid] = incl - v;
    }
    __syncthreads();
    for (int i = gtid; i < N; i += gsz) {
        int r = rowptr[i] + boff[i >> 10];
        rowptr[i] = r;
        cursor[i] = r;
    }
    if (gtid == 0) rowptr[N] = E;
    gg.sync();

    // ---- P4: counting-sort scatter ----
    for (int i = gtid; i < E; i += gsz) {
        int p = atomicAdd(&cursor[edst[i]], 1);
        ssrc[p] = esrc[i];
    }
    gg.sync();

    // ---- P5: CSR aggregation (one wave per node, grid-stride) ----
    {
        const int gw = bid * 4 + w;
        const int nW = nBlk * 4;
        for (int n = gw; n < N; n += nW) {
            int rp0 = rowptr[n], rp1 = rowptr[n + 1];
            unsigned int ydu = *(const unsigned int*)(Yd + (long)n * D + lane * 2);
            float yd0 = bflo(ydu), yd1 = bfhi(ydu);
            float a0 = 0.f, a1 = 0.f;
            int e = rp0;
            for (; e + 4 <= rp1; e += 4) {
                int s0 = ssrc[e], s1 = ssrc[e + 1], s2 = ssrc[e + 2], s3 = ssrc[e + 3];
                unsigned int u0 = *(const unsigned int*)(Ys + (long)s0 * D + lane * 2);
                unsigned int u1 = *(const unsigned int*)(Ys + (long)s1 * D + lane * 2);
                unsigned int u2 = *(const unsigned int*)(Ys + (long)s2 * D + lane * 2);
                unsigned int u3 = *(const unsigned int*)(Ys + (long)s3 * D + lane * 2);
                a0 += fmaxf(bflo(u0) + yd0, 0.f); a1 += fmaxf(bfhi(u0) + yd1, 0.f);
                a0 += fmaxf(bflo(u1) + yd0, 0.f); a1 += fmaxf(bfhi(u1) + yd1, 0.f);
                a0 += fmaxf(bflo(u2) + yd0, 0.f); a1 += fmaxf(bfhi(u2) + yd1, 0.f);
                a0 += fmaxf(bflo(u3) + yd0, 0.f); a1 += fmaxf(bfhi(u3) + yd1, 0.f);
            }
            for (; e < rp1; e++) {
                int s0 = ssrc[e];
                unsigned int u0 = *(const unsigned int*)(Ys + (long)s0 * D + lane * 2);
                a0 += fmaxf(bflo(u0) + yd0, 0.f); a1 += fmaxf(bfhi(u0) + yd1, 0.f);
            }
            unsigned int o = (unsigned int)f2bf(a0) | ((unsigned int)f2bf(a1) << 16);
            *(unsigned int*)(aggb + (long)n * D + lane * 2) = o;
        }
    }
    gg.sync();

    // ---- P6: gemm2 ----
    {
        short8 wf[8][2];
#pragma unroll
        for (int kk = 0; kk < 8; kk++)
#pragma unroll
            for (int c = 0; c < 2; c++)
                wf[kk][c] = ((const short8*)w2f)[(kk * 8 + w * 2 + c) * 64 + lane];
        float bias[2];
        bias[0] = b2[(w * 2) * 16 + col];
        bias[1] = b2[(w * 2 + 1) * 16 + col];

        for (int t = bid; t < nTiles; t += nBlk) {
            const int n0 = t * 16;
            int nr = n0 + col; if (nr >= N) nr = N - 1;
            floatx4 acc[2];
#pragma unroll
            for (int c = 0; c < 2; c++)
#pragma unroll
                for (int q = 0; q < 4; q++) acc[c][q] = 0.f;
#pragma unroll
            for (int kk = 0; kk < 8; kk++) {
                short8 a;
                if (kk < 4)
                    a = cvt8(x + (long)nr * D + kk * 32 + quad * 8);
                else
                    a = *(const short8*)(aggb + (long)nr * D + (kk - 4) * 32 + quad * 8);
                acc[0] = __builtin_amdgcn_mfma_f32_16x16x32_bf16(a, wf[kk][0], acc[0], 0, 0, 0);
                acc[1] = __builtin_amdgcn_mfma_f32_16x16x32_bf16(a, wf[kk][1], acc[1], 0, 0, 0);
            }
#pragma unroll
            for (int c = 0; c < 2; c++)
#pragma unroll
                for (int r = 0; r < 4; r++) {
                    int n = n0 + quad * 4 + r;
                    if (n < N) {
                        long idx = (long)n * D + (w * 2 + c) * 16 + col;
                        float v = acc[c][r] + bias[c];
                        v = v > 0.f ? v : 0.f;
                        out[idx] = x[idx] + v;
                    }
                }
        }
    }
}

// ---------------- fallback path (R5, proven) ----------------
__global__ void k_convert_w(const float* __restrict__ W1, const float* __restrict__ W2,
                            unsigned short* __restrict__ w1f, unsigned short* __restrict__ w2f,
                            int* __restrict__ cnt, int N) {
    int gid = blockIdx.x * blockDim.x + threadIdx.x;
    if (gid < N) cnt[gid] = 0;
    if (gid < 32768) {
        int tid = gid;
        int j = tid & 7, lane = (tid >> 3) & 63, ct = (tid >> 9) & 15, kk = tid >> 13;
        int k = kk * 32 + (lane >> 4) * 8 + j;
        int c = ct * 16 + (lane & 15);
        float v = (c < 128) ? W1[k * 128 + c] : W1[(128 + k) * 128 + (c - 128)];
        w1f[tid] = f2bf(v);
    } else if (gid < 65536) {
        int tid = gid - 32768;
        int j = tid & 7, lane = (tid >> 3) & 63, ct = (tid >> 9) & 7, kk = tid >> 12;
        int k = kk * 32 + (lane >> 4) * 8 + j;
        int c = ct * 16 + (lane & 15);
        int row = (k < 128) ? k : (128 + ((k - 128) & 7) * 16 + ((k - 128) >> 3));
        w2f[tid] = f2bf(W2[row * 128 + c]);
    }
}

__global__ __launch_bounds__(256) void k_gemm1(
    const float* __restrict__ x, const unsigned short* __restrict__ w1f,
    const float* __restrict__ b1, unsigned short* __restrict__ Ys,
    unsigned short* __restrict__ Yd, int N, int nTiles)
{
    const int tid = threadIdx.x, w = tid >> 6, lane = tid & 63;
    const int quad = lane >> 4, col = lane & 15;
    short8 wf[4][4];
#pragma unroll
    for (int kk = 0; kk < 4; kk++)
#pragma unroll
        for (int j = 0; j < 4; j++)
            wf[kk][j] = ((const short8*)w1f)[(kk * 16 + w * 4 + j) * 64 + lane];
    float bias[4];
#pragma unroll
    for (int j = 0; j < 4; j++)
        bias[j] = (w >= 2) ? b1[(((w & 1) * 4 + j)) * 16 + col] : 0.f;
    unsigned short* Yhalf = (w < 2) ? Ys : Yd;
    const int ctb = (w & 1) * 4;
    for (int t = blockIdx.x; t < nTiles; t += gridDim.x) {
        const int n0 = t * 16;
        int nr = n0 + col; if (nr >= N) nr = N - 1;
        floatx4 acc[4];
#pragma unroll
        for (int j = 0; j < 4; j++)
#pragma unroll
            for (int q = 0; q < 4; q++) acc[j][q] = 0.f;
#pragma unroll
        for (int kk = 0; kk < 4; kk++) {
            short8 a = cvt8(x + (long)nr * D + kk * 32 + quad * 8);
#pragma unroll
            for (int j = 0; j < 4; j++)
                acc[j] = __builtin_amdgcn_mfma_f32_16x16x32_bf16(a, wf[kk][j], acc[j], 0, 0, 0);
        }
#pragma unroll
        for (int r = 0; r < 4; r++) {
            int n = n0 + quad * 4 + r;
            if (n < N) {
                ushort4 o;
                o.x = f2bf(acc[0][r] + bias[0]);
                o.y = f2bf(acc[1][r] + bias[1]);
                o.z = f2bf(acc[2][r] + bias[2]);
                o.w = f2bf(acc[3][r] + bias[3]);
                *(ushort4*)(Yhalf + (long)n * D + col * 8 + ctb) = o;
            }
        }
    }
}

__global__ void k_hist(const int* __restrict__ dst, int* __restrict__ cnt, int E) {
    int i = blockIdx.x * blockDim.x + threadIdx.x;
    if (i < E) atomicAdd(&cnt[dst[i]], 1);
}

__global__ __launch_bounds__(1024) void k_scanA(const int* __restrict__ cnt,
                                                int* __restrict__ rowptr,
                                                int* __restrict__ bsum, int N) {
    __shared__ int s[1024];
    int tid = threadIdx.x, i = blockIdx.x * 1024 + tid;
    int c = (i < N) ? cnt[i] : 0;
    s[tid] = c; __syncthreads();
    for (int off = 1; off < 1024; off <<= 1) {
        int t = (tid >= off) ? s[tid - off] : 0;
        __syncthreads();
        s[tid] += t;
        __syncthreads();
    }
    if (i < N) rowptr[i] = s[tid] - c;
    if (tid == 1023) bsum[blockIdx.x] = s[1023];
}

__global__ void k_scanB(int* __restrict__ bsum, int nb) {
    int lane = threadIdx.x;
    int v = (lane < nb) ? bsum[lane] : 0;
    int incl = v;
    for (int off = 1; off < 64; off <<= 1) {
        int t = __shfl_up(incl, off, 64);
        if (lane >= off) incl += t;
    }
    if (lane < nb) bsum[lane] = incl - v;
}

__global__ void k_scanC(int* __restrict__ rowptr, int* __restrict__ cursor,
                        const int* __restrict__ bsum, int N, int E) {
    int i = blockIdx.x * blockDim.x + threadIdx.x;
    if (i < N) {
        int r = rowptr[i] + bsum[i >> 10];
        rowptr[i] = r;
        cursor[i] = r;
    }
    if (i == 0) rowptr[N] = E;
}

__global__ void k_scatter(const int* __restrict__ src, const int* __restrict__ dst,
                          int* __restrict__ cursor, int* __restrict__ ssrc, int E) {
    int i = blockIdx.x * blockDim.x + threadIdx.x;
    if (i < E) {
        int p = atomicAdd(&cursor[dst[i]], 1);
        ssrc[p] = src[i];
    }
}

__global__ __launch_bounds__(256) void k_agg(
    const unsigned short* __restrict__ Ys, const unsigned short* __restrict__ Yd,
    const int* __restrict__ rowptr, const int* __restrict__ ssrc,
    unsigned short* __restrict__ aggb, int N)
{
    int wv = blockIdx.x * 4 + (threadIdx.x >> 6);
    if (wv >= N) return;
    int lane = threadIdx.x & 63;
    int rp0 = rowptr[wv], rp1 = rowptr[wv + 1];
    unsigned int ydu = *(const unsigned int*)(Yd + (long)wv * D + lane * 2);
    float yd0 = bflo(ydu), yd1 = bfhi(ydu);
    float a0 = 0.f, a1 = 0.f;
    int e = rp0;
    for (; e + 4 <= rp1; e += 4) {
        int s0 = ssrc[e], s1 = ssrc[e + 1], s2 = ssrc[e + 2], s3 = ssrc[e + 3];
        unsigned int u0 = *(const unsigned int*)(Ys + (long)s0 * D + lane * 2);
        unsigned int u1 = *(const unsigned int*)(Ys + (long)s1 * D + lane * 2);
        unsigned int u2 = *(const unsigned int*)(Ys + (long)s2 * D + lane * 2);
        unsigned int u3 = *(const unsigned int*)(Ys + (long)s3 * D + lane * 2);
        a0 += fmaxf(bflo(u0) + yd0, 0.f); a1 += fmaxf(bfhi(u0) + yd1, 0.f);
        a0 += fmaxf(bflo(u1) + yd0, 0.f); a1 += fmaxf(bfhi(u1) + yd1, 0.f);
        a0 += fmaxf(bflo(u2) + yd0, 0.f); a1 += fmaxf(bfhi(u2) + yd1, 0.f);
        a0 += fmaxf(bflo(u3) + yd0, 0.f); a1 += fmaxf(bfhi(u3) + yd1, 0.f);
    }
    for (; e < rp1; e++) {
        int s0 = ssrc[e];
        unsigned int u0 = *(const unsigned int*)(Ys + (long)s0 * D + lane * 2);
        a0 += fmaxf(bflo(u0) + yd0, 0.f); a1 += fmaxf(bfhi(u0) + yd1, 0.f);
    }
    unsigned int o = (unsigned int)f2bf(a0) | ((unsigned int)f2bf(a1) << 16);
    *(unsigned int*)(aggb + (long)wv * D + lane * 2) = o;
}

__global__ __launch_bounds__(256) void k_gemm2(
    const float* __restrict__ x, const unsigned short* __restrict__ aggb,
    const unsigned short* __restrict__ w2f, const float* __restrict__ b2,
    float* __restrict__ out, int N, int nTiles)
{
    const int tid = threadIdx.x, w = tid >> 6, lane = tid & 63;
    const int quad = lane >> 4, col = lane & 15;
    short8 wf[8][2];
#pragma unroll
    for (int kk = 0; kk < 8; kk++)
#pragma unroll
        for (int c = 0; c < 2; c++)
            wf[kk][c] = ((const short8*)w2f)[(kk * 8 + w * 2 + c) * 64 + lane];
    float bias[2];
    bias[0] = b2[(w * 2) * 16 + col];
    bias[1] = b2[(w * 2 + 1) * 16 + col];
    for (int t = blockIdx.x; t < nTiles; t += gridDim.x) {
        const int n0 = t * 16;
        int nr = n0 + col; if (nr >= N) nr = N - 1;
        floatx4 acc[2];
#pragma unroll
        for (int c = 0; c < 2; c++)
#pragma unroll
            for (int q = 0; q < 4; q++) acc[c][q] = 0.f;
#pragma unroll
        for (int kk = 0; kk < 8; kk++) {
            short8 a;
            if (kk < 4)
                a = cvt8(x + (long)nr * D + kk * 32 + quad * 8);
            else
                a = *(const short8*)(aggb + (long)nr * D + (kk - 4) * 32 + quad * 8);
            acc[0] = __builtin_amdgcn_mfma_f32_16x16x32_bf16(a, wf[kk][0], acc[0], 0, 0, 0);
            acc[1] = __builtin_amdgcn_mfma_f32_16x16x32_bf16(a, wf[kk][1], acc[1], 0, 0, 0);
        }
#pragma unroll
        for (int c = 0; c < 2; c++)
#pragma unroll
            for (int r = 0; r < 4; r++) {
                int n = n0 + quad * 4 + r;
                if (n < N) {
                    long idx = (long)n * D + (w * 2 + c) * 16 + col;
                    float v = acc[c][r] + bias[c];
                    v = v > 0.f ? v : 0.f;
                    out[idx] = x[idx] + v;
                }
            }
    }
}

extern "C" void kernel_launch(void* const* d_in, const int* in_sizes, int n_in,
                              void* d_out, int out_size, void* d_ws, size_t ws_size,
                              hipStream_t stream)
{
    const float* x   = (const float*)d_in[0];
    const int* esrc  = (const int*)d_in[1];
    const int* edst  = (const int*)d_in[2];
    const float* W1  = (const float*)d_in[3];
    const float* b1  = (const float*)d_in[4];
    const float* W2  = (const float*)d_in[5];
    const float* b2  = (const float*)d_in[6];
    float* out = (float*)d_out;

    const int ND = in_sizes[0];     // N*D
    int N  = ND / D;                // 50000
    int E  = in_sizes[1];           // 600000

    // workspace carve-out (256B-aligned), total ~42 MB
    char* p = (char*)d_ws;
    auto alloc = [&](size_t bytes) { char* r = p; p += (bytes + 255) & ~(size_t)255; return r; };
    unsigned short* Ys   = (unsigned short*)alloc((size_t)ND * 2);
    unsigned short* Yd   = (unsigned short*)alloc((size_t)ND * 2);
    unsigned short* aggb = (unsigned short*)alloc((size_t)ND * 2);
    unsigned short* w1f  = (unsigned short*)alloc(32768 * 2);
    unsigned short* w2f  = (unsigned short*)alloc(32768 * 2);
    int* rowptr = (int*)alloc((size_t)(N + 1) * 4);
    int* cursor = (int*)alloc((size_t)N * 4);
    int* cnt    = (int*)alloc((size_t)N * 4);
    int* bsum   = (int*)alloc(64 * 4);
    int* ssrc   = (int*)alloc((size_t)E * 4);

    int nTiles = (N + 15) / 16;   // 3125

    // occupancy-clamped cooperative grid (MI355X: 256 CUs)
    int perCU = 0;
    hipError_t oe = hipOccupancyMaxActiveBlocksPerMultiprocessor(&perCU, k_fused, 256, 0);
    if (oe != hipSuccess || perCU < 1) perCU = 2;
    long maxB = (long)perCU * 256;
    int gridB = (int)(maxB < 1024 ? maxB : 1024);

    void* args[] = {
        (void*)&x, (void*)&esrc, (void*)&edst, (void*)&W1, (void*)&b1,
        (void*)&W2, (void*)&b2, (void*)&out,
        (void*)&Ys, (void*)&Yd, (void*)&aggb, (void*)&w1f, (void*)&w2f,
        (void*)&rowptr, (void*)&cursor, (void*)&cnt, (void*)&bsum, (void*)&ssrc,
        (void*)&N, (void*)&E, (void*)&nTiles
    };
    hipError_t le = hipLaunchCooperativeKernel((const void*)k_fused, dim3(gridB), dim3(256),
                                               args, 0, stream);
    if (le != hipSuccess) {
        // fallback: R5 proven 9-dispatch path
        k_convert_w<<<256, 256, 0, stream>>>(W1, W2, w1f, w2f, cnt, N);
        k_gemm1<<<640, 256, 0, stream>>>(x, w1f, b1, Ys, Yd, N, nTiles);
        k_hist<<<(E + 255) / 256, 256, 0, stream>>>(edst, cnt, E);
        const int nb = (N + 1023) / 1024;
        k_scanA<<<nb, 1024, 0, stream>>>(cnt, rowptr, bsum, N);
        k_scanB<<<1, 64, 0, stream>>>(bsum, nb);
        k_scanC<<<(N + 255) / 256, 256, 0, stream>>>(rowptr, cursor, bsum, N, E);
        k_scatter<<<(E + 255) / 256, 256, 0, stream>>>(esrc, edst, cursor, ssrc, E);
        k_agg<<<(N + 3) / 4, 256, 0, stream>>>(Ys, Yd, rowptr, ssrc, aggb, N);
        k_gemm2<<<640, 256, 0, stream>>>(x, aggb, w2f, b2, out, N, nTiles);
    }
}

// Round 7
// 238.865 us; speedup vs baseline: 2.5553x; 2.5553x over previous
//
#include <hip/hip_runtime.h>
#include <stdint.h>

// RelationalMSG (R7): R5 pipeline with sync-free local fusions.
//   memset cnt=0
//   k_gemm1h : hist(dst) + [Ys|Yd] = x@[W1a|W1b] (+b1), W1 frags converted in-kernel
//   k_scanA  : per-1024-chunk exclusive scan
//   k_scanBC : chunk-offset scan (redundant per block) + apply -> rowptr, cursor
//   k_scatter: counting-sort scatter (ssrc grouped by dst)
//   k_agg2   : per-16-node tile: CSR aggregate -> LDS, barrier, gemm2 from LDS
//              (aggb round-trip eliminated; W2 frags converted in-kernel)
// Ys/Yd in column-permuted layout pos = c16*8 + ct; inverse baked into the in-kernel
// W2 fragment conversion. N=50000, E=600000, D=128. 6 kernels + 1 memset.

typedef __attribute__((ext_vector_type(8))) short short8;   // 8 bf16 (MFMA A/B frag)
typedef __attribute__((ext_vector_type(4))) float floatx4;  // MFMA C/D frag

#define D 128
#define SPAD 136   // LDS row stride in shorts (272B): 2-way max bank aliasing on writes

static __device__ __forceinline__ unsigned short f2bf(float f) {
    union { float f; unsigned int u; } v; v.f = f;
    unsigned int r = (v.u + 0x7fffu + ((v.u >> 16) & 1u)) >> 16; // RNE
    return (unsigned short)r;
}
static __device__ __forceinline__ float bflo(unsigned int u) {
    union { unsigned int u; float f; } v; v.u = u << 16; return v.f;
}
static __device__ __forceinline__ float bfhi(unsigned int u) {
    union { unsigned int u; float f; } v; v.u = u & 0xffff0000u; return v.f;
}
static __device__ __forceinline__ short8 cvt8(const float* p) {
    float4 f0 = *(const float4*)p;
    float4 f1 = *(const float4*)(p + 4);
    short8 t;
    t[0] = (short)f2bf(f0.x); t[1] = (short)f2bf(f0.y);
    t[2] = (short)f2bf(f0.z); t[3] = (short)f2bf(f0.w);
    t[4] = (short)f2bf(f1.x); t[5] = (short)f2bf(f1.y);
    t[6] = (short)f2bf(f1.z); t[7] = (short)f2bf(f1.w);
    return t;
}

// hist + gemm1. Wave w owns out-cols [w*64, w*64+64) of the 256-wide [W1a|W1b];
// B-fragments built directly from W1 (fp32, L2-resident).
__global__ __launch_bounds__(256) void k_gemm1h(
    const float* __restrict__ x,
    const float* __restrict__ W1,
    const float* __restrict__ b1,
    const int* __restrict__ edst,
    int* __restrict__ cnt,
    unsigned short* __restrict__ Ys,
    unsigned short* __restrict__ Yd,
    int N, int E, int nTiles)
{
    const int tid = threadIdx.x, w = tid >> 6, lane = tid & 63;
    const int quad = lane >> 4, col = lane & 15;
    const int gtid = blockIdx.x * 256 + tid;
    const int gsz  = gridDim.x * 256;

    // histogram (independent of GEMM work)
    for (int i = gtid; i < E; i += gsz) atomicAdd(&cnt[edst[i]], 1);

    // build this wave's 16 B-fragments from W1
    // frag(kk,j2)[j] = B1[kk*32+quad*8+j][(w*4+j2)*16+col], B1[k][c] = c<128 ? W1[k][c] : W1[128+k][c-128]
    short8 wf[4][4];
#pragma unroll
    for (int kk = 0; kk < 4; kk++)
#pragma unroll
        for (int j2 = 0; j2 < 4; j2++) {
            int c = (w * 4 + j2) * 16 + col;
            const float* base = (c < 128) ? (W1 + c) : (W1 + 128 * 128 + (c - 128));
            short8 t;
#pragma unroll
            for (int j = 0; j < 8; j++) {
                int k = kk * 32 + quad * 8 + j;
                t[j] = (short)f2bf(base[k * 128]);
            }
            wf[kk][j2] = t;
        }
    float bias[4];
#pragma unroll
    for (int j = 0; j < 4; j++)
        bias[j] = (w >= 2) ? b1[(((w & 1) * 4 + j)) * 16 + col] : 0.f;
    unsigned short* Yhalf = (w < 2) ? Ys : Yd;
    const int ctb = (w & 1) * 4;   // permuted store base: pos = col16*8 + ct

    for (int t = blockIdx.x; t < nTiles; t += gridDim.x) {
        const int n0 = t * 16;
        int nr = n0 + col; if (nr >= N) nr = N - 1;
        floatx4 acc[4];
#pragma unroll
        for (int j = 0; j < 4; j++)
#pragma unroll
            for (int q = 0; q < 4; q++) acc[j][q] = 0.f;
#pragma unroll
        for (int kk = 0; kk < 4; kk++) {
            short8 a = cvt8(x + (long)nr * D + kk * 32 + quad * 8);
#pragma unroll
            for (int j = 0; j < 4; j++)
                acc[j] = __builtin_amdgcn_mfma_f32_16x16x32_bf16(a, wf[kk][j], acc[j], 0, 0, 0);
        }
#pragma unroll
        for (int r = 0; r < 4; r++) {
            int n = n0 + quad * 4 + r;
            if (n < N) {
                ushort4 o;
                o.x = f2bf(acc[0][r] + bias[0]);
                o.y = f2bf(acc[1][r] + bias[1]);
                o.z = f2bf(acc[2][r] + bias[2]);
                o.w = f2bf(acc[3][r] + bias[3]);
                *(ushort4*)(Yhalf + (long)n * D + col * 8 + ctb) = o;
            }
        }
    }
}

__global__ __launch_bounds__(1024) void k_scanA(const int* __restrict__ cnt,
                                                int* __restrict__ rowptr,
                                                int* __restrict__ bsum, int N) {
    __shared__ int s[1024];
    int tid = threadIdx.x, i = blockIdx.x * 1024 + tid;
    int c = (i < N) ? cnt[i] : 0;
    s[tid] = c; __syncthreads();
    for (int off = 1; off < 1024; off <<= 1) {
        int t = (tid >= off) ? s[tid - off] : 0;
        __syncthreads();
        s[tid] += t;
        __syncthreads();
    }
    if (i < N) rowptr[i] = s[tid] - c;           // exclusive within block
    if (tid == 1023) bsum[blockIdx.x] = s[1023]; // block total
}

// scanB+scanC fused: each block's first wave redundantly scans bsum (nChunk<=64),
// picks its own chunk offset, then applies it.
__global__ __launch_bounds__(1024) void k_scanBC(int* __restrict__ rowptr,
                                                 int* __restrict__ cursor,
                                                 const int* __restrict__ bsum,
                                                 int N, int E, int nChunk) {
    __shared__ int off;
    const int tid = threadIdx.x;
    if (tid < 64) {
        int v = (tid < nChunk) ? bsum[tid] : 0;
        int incl = v;
        for (int o = 1; o < 64; o <<= 1) {
            int t = __shfl_up(incl, o, 64);
            if (tid >= o) incl += t;
        }
        if (tid == blockIdx.x) off = incl - v;   // exclusive prefix for this chunk
    }
    __syncthreads();
    int i = blockIdx.x * 1024 + tid;
    if (i < N) {
        int r = rowptr[i] + off;
        rowptr[i] = r;
        cursor[i] = r;
    }
    if (i == 0) rowptr[N] = E;
}

__global__ void k_scatter(const int* __restrict__ src, const int* __restrict__ dst,
                          int* __restrict__ cursor, int* __restrict__ ssrc, int E) {
    int i = blockIdx.x * blockDim.x + threadIdx.x;
    if (i < E) {
        int p = atomicAdd(&cursor[dst[i]], 1);
        ssrc[p] = src[i];
    }
}

// Fused CSR-aggregate + gemm2 per 16-node tile.
// Phase A: wave w aggregates nodes n0+w*4..+3 into LDS (permuted col layout).
// Phase B: gemm2 -> out = x + relu([x;agg]@W2+b2); agg-half of A read from LDS.
__global__ __launch_bounds__(256) void k_agg2(
    const float* __restrict__ x,
    const float* __restrict__ W2,
    const float* __restrict__ b2,
    const unsigned short* __restrict__ Ys,
    const unsigned short* __restrict__ Yd,
    const int* __restrict__ rowptr,
    const int* __restrict__ ssrc,
    float* __restrict__ out,
    int N, int nTiles)
{
    __shared__ unsigned short sagg[16][SPAD];
    const int tid = threadIdx.x, w = tid >> 6, lane = tid & 63;
    const int quad = lane >> 4, col = lane & 15;

    // build this wave's 16 B-fragments from W2 (k>=128 rows un-permute agg cols)
    // frag(kk,c2)[j] = W2[row(kk*32+quad*8+j)][(w*2+c2)*16+col]
    short8 wf[8][2];
#pragma unroll
    for (int kk = 0; kk < 8; kk++)
#pragma unroll
        for (int c2 = 0; c2 < 2; c2++) {
            int c = (w * 2 + c2) * 16 + col;
            short8 t;
#pragma unroll
            for (int j = 0; j < 8; j++) {
                int k = kk * 32 + quad * 8 + j;
                int row = (k < 128) ? k : (128 + ((k - 128) & 7) * 16 + ((k - 128) >> 3));
                t[j] = (short)f2bf(W2[row * 128 + c]);
            }
            wf[kk][c2] = t;
        }
    float bias[2];
    bias[0] = b2[(w * 2) * 16 + col];
    bias[1] = b2[(w * 2 + 1) * 16 + col];

    for (int t = blockIdx.x; t < nTiles; t += gridDim.x) {
        const int n0 = t * 16;
        // ---- Phase A: aggregate this block's 16 nodes into LDS ----
#pragma unroll
        for (int i = 0; i < 4; i++) {
            int n = n0 + w * 4 + i;
            if (n < N) {
                int rp0 = rowptr[n], rp1 = rowptr[n + 1];
                unsigned int ydu = *(const unsigned int*)(Yd + (long)n * D + lane * 2);
                float yd0 = bflo(ydu), yd1 = bfhi(ydu);
                float a0 = 0.f, a1 = 0.f;
                int e = rp0;
                for (; e + 4 <= rp1; e += 4) {
                    int s0 = ssrc[e], s1 = ssrc[e + 1], s2 = ssrc[e + 2], s3 = ssrc[e + 3];
                    unsigned int u0 = *(const unsigned int*)(Ys + (long)s0 * D + lane * 2);
                    unsigned int u1 = *(const unsigned int*)(Ys + (long)s1 * D + lane * 2);
                    unsigned int u2 = *(const unsigned int*)(Ys + (long)s2 * D + lane * 2);
                    unsigned int u3 = *(const unsigned int*)(Ys + (long)s3 * D + lane * 2);
                    a0 += fmaxf(bflo(u0) + yd0, 0.f); a1 += fmaxf(bfhi(u0) + yd1, 0.f);
                    a0 += fmaxf(bflo(u1) + yd0, 0.f); a1 += fmaxf(bfhi(u1) + yd1, 0.f);
                    a0 += fmaxf(bflo(u2) + yd0, 0.f); a1 += fmaxf(bfhi(u2) + yd1, 0.f);
                    a0 += fmaxf(bflo(u3) + yd0, 0.f); a1 += fmaxf(bfhi(u3) + yd1, 0.f);
                }
                for (; e < rp1; e++) {
                    int s0 = ssrc[e];
                    unsigned int u0 = *(const unsigned int*)(Ys + (long)s0 * D + lane * 2);
                    a0 += fmaxf(bflo(u0) + yd0, 0.f); a1 += fmaxf(bfhi(u0) + yd1, 0.f);
                }
                unsigned int o = (unsigned int)f2bf(a0) | ((unsigned int)f2bf(a1) << 16);
                *(unsigned int*)&sagg[w * 4 + i][lane * 2] = o;
            }
        }
        __syncthreads();

        // ---- Phase B: gemm2 on the tile ----
        int nr = n0 + col; if (nr >= N) nr = N - 1;
        floatx4 acc[2];
#pragma unroll
        for (int c = 0; c < 2; c++)
#pragma unroll
            for (int q = 0; q < 4; q++) acc[c][q] = 0.f;
#pragma unroll
        for (int kk = 0; kk < 8; kk++) {
            short8 a;
            if (kk < 4)
                a = cvt8(x + (long)nr * D + kk * 32 + quad * 8);
            else
                a = *(const short8*)&sagg[col][(kk - 4) * 32 + quad * 8];
            acc[0] = __builtin_amdgcn_mfma_f32_16x16x32_bf16(a, wf[kk][0], acc[0], 0, 0, 0);
            acc[1] = __builtin_amdgcn_mfma_f32_16x16x32_bf16(a, wf[kk][1], acc[1], 0, 0, 0);
        }
#pragma unroll
        for (int c = 0; c < 2; c++)
#pragma unroll
            for (int r = 0; r < 4; r++) {
                int n = n0 + quad * 4 + r;
                if (n < N) {
                    long idx = (long)n * D + (w * 2 + c) * 16 + col;
                    float v = acc[c][r] + bias[c];
                    v = v > 0.f ? v : 0.f;
                    out[idx] = x[idx] + v;
                }
            }
        __syncthreads();   // protect sagg before next tile's Phase A
    }
}

extern "C" void kernel_launch(void* const* d_in, const int* in_sizes, int n_in,
                              void* d_out, int out_size, void* d_ws, size_t ws_size,
                              hipStream_t stream)
{
    const float* x   = (const float*)d_in[0];
    const int* esrc  = (const int*)d_in[1];
    const int* edst  = (const int*)d_in[2];
    const float* W1  = (const float*)d_in[3];
    const float* b1  = (const float*)d_in[4];
    const float* W2  = (const float*)d_in[5];
    const float* b2  = (const float*)d_in[6];
    float* out = (float*)d_out;

    const int ND = in_sizes[0];     // N*D
    const int N  = ND / D;          // 50000
    const int E  = in_sizes[1];     // 600000

    // workspace carve-out (256B-aligned), ~28 MB
    char* p = (char*)d_ws;
    auto alloc = [&](size_t bytes) { char* r = p; p += (bytes + 255) & ~(size_t)255; return r; };
    unsigned short* Ys = (unsigned short*)alloc((size_t)ND * 2);
    unsigned short* Yd = (unsigned short*)alloc((size_t)ND * 2);
    int* rowptr = (int*)alloc((size_t)(N + 1) * 4);
    int* cursor = (int*)alloc((size_t)N * 4);
    int* cnt    = (int*)alloc((size_t)N * 4);
    int* bsum   = (int*)alloc(64 * 4);
    int* ssrc   = (int*)alloc((size_t)E * 4);

    const int nTiles = (N + 15) / 16;     // 3125
    const int nChunk = (N + 1023) / 1024; // 49

    hipMemsetAsync(cnt, 0, (size_t)N * 4, stream);
    k_gemm1h<<<1024, 256, 0, stream>>>(x, W1, b1, edst, cnt, Ys, Yd, N, E, nTiles);
    k_scanA<<<nChunk, 1024, 0, stream>>>(cnt, rowptr, bsum, N);
    k_scanBC<<<nChunk, 1024, 0, stream>>>(rowptr, cursor, bsum, N, E, nChunk);
    k_scatter<<<(E + 255) / 256, 256, 0, stream>>>(esrc, edst, cursor, ssrc, E);
    k_agg2<<<1024, 256, 0, stream>>>(x, W2, b2, Ys, Yd, rowptr, ssrc, out, N, nTiles);
}